// Round 6
// baseline (262.739 us; speedup 1.0000x reference)
//
#include <hip/hip_runtime.h>
#include <math.h>

#define N_NODES 16384
#define D_MODEL 256
#define H_HEADS 4
#define C_CH 256
#define E_EDGES 65536
#define ETOT (E_EDGES + N_NODES)
#define HC 1024

typedef __bf16 bf16x8 __attribute__((ext_vector_type(8)));
typedef __bf16 bf16x4 __attribute__((ext_vector_type(4)));
typedef float f32x4 __attribute__((ext_vector_type(4)));

__device__ __forceinline__ __bf16 f2bf(float f) { return (__bf16)f; }
__device__ __forceinline__ float bf2f(__bf16 b) { return (float)b; }

// ---- prep: blocks 0..63 compose Wc2[c][h*256+d] + bias_agg; 64..127 cast W2 ----
__global__ __launch_bounds__(256) void prep_w(
    const float* __restrict__ Wg, const float* __restrict__ W1,
    const float* __restrict__ b1, const float* __restrict__ bg,
    const float* __restrict__ W2, __bf16* __restrict__ Wc2,
    float* __restrict__ bias_agg, __bf16* __restrict__ W2_bf)
{
    int b = blockIdx.x;
    int tid = threadIdx.x;
    if (b >= 64) {   // cast W2
        int i = (b - 64) * 1024 + tid * 4;
        float4 v = *(const float4*)(W2 + i);
        bf16x4 o;
        o[0] = f2bf(v.x); o[1] = f2bf(v.y); o[2] = f2bf(v.z); o[3] = f2bf(v.w);
        *(bf16x4*)(W2_bf + i) = o;
        return;
    }
    int cg = b * 4;      // 4 c-values per block
    int d  = tid;
    // Wc[h*256+c][d] = sum_k Wg[h*256+c][k] * W1[k][d]
    float acc[16] = {};  // [h][ci]
    for (int k = 0; k < 256; ++k) {
        float w1v = W1[(size_t)k * 256 + d];
        #pragma unroll
        for (int h = 0; h < 4; ++h)
            #pragma unroll
            for (int ci = 0; ci < 4; ++ci)
                acc[h * 4 + ci] = fmaf(Wg[(size_t)(h * 256 + cg + ci) * 256 + k], w1v,
                                       acc[h * 4 + ci]);
    }
    #pragma unroll
    for (int h = 0; h < 4; ++h)
        #pragma unroll
        for (int ci = 0; ci < 4; ++ci)
            Wc2[(size_t)(cg + ci) * 1024 + h * 256 + d] = f2bf(acc[h * 4 + ci]);

    // bias_agg[c] = 0.25 * sum_h dot(Wg[h*256+c,:], b1) + bg[c]
    __shared__ float red[16][4];
    float b1v = b1[d];
    int lane = tid & 63, wid = tid >> 6;
    #pragma unroll
    for (int r = 0; r < 16; ++r) {   // r = h*4+ci
        int o = (r >> 2) * 256 + cg + (r & 3);
        float p = Wg[(size_t)o * 256 + d] * b1v;
        for (int s = 32; s; s >>= 1) p += __shfl_xor(p, s);
        if (lane == 0) red[r][wid] = p;
    }
    __syncthreads();
    if (tid < 4) {
        float s = 0.f;
        #pragma unroll
        for (int h = 0; h < 4; ++h) {
            int r = h * 4 + tid;
            s += red[r][0] + red[r][1] + red[r][2] + red[r][3];
        }
        bias_agg[cg + tid] = 0.25f * s + bg[cg + tid];
    }
}

// ---- t[v][d] = sum_c att[h][c] * Wg[h*256+c][d]   (v<4: src, v>=4: dst) ----
__global__ __launch_bounds__(256) void make_t(
    const float* __restrict__ Wg, const float* __restrict__ att_src,
    const float* __restrict__ att_dst, float* __restrict__ t)
{
    int v = blockIdx.x, h = v & 3;
    int d = threadIdx.x;
    const float* att = ((v < 4) ? att_src : att_dst) + h * C_CH;
    float acc = 0.f;
    for (int c = 0; c < 256; ++c)
        acc = fmaf(Wg[(size_t)(h * 256 + c) * 256 + d], att[c], acc);
    t[v * 256 + d] = acc;
}

// ---- u2[v][d] = sum_k t[v][k] * W1[k][d];  c0[v] = dot(t[v], b1) ----
__global__ __launch_bounds__(256) void make_u2(
    const float* __restrict__ t, const float* __restrict__ W1,
    const float* __restrict__ b1, float* __restrict__ u2, float* __restrict__ c0)
{
    int v = blockIdx.x;
    int d = threadIdx.x;
    const float* tv = t + v * 256;
    float acc = 0.f;
    for (int k = 0; k < 256; ++k)
        acc = fmaf(tv[k], W1[(size_t)k * 256 + d], acc);
    u2[v * 256 + d] = acc;
    // c0
    __shared__ float red[4];
    int lane = d & 63, wid = d >> 6;
    float p = tv[d] * b1[d];
    for (int s = 32; s; s >>= 1) p += __shfl_xor(p, s);
    if (lane == 0) red[wid] = p;
    __syncthreads();
    if (d == 0) c0[v] = red[0] + red[1] + red[2] + red[3];
}

// ------- LayerNorm + fused attention logits: one row per wave -------
__global__ __launch_bounds__(256) void ln_logits(
    const float* __restrict__ in, const float* __restrict__ gamma,
    const float* __restrict__ beta, const float* __restrict__ u2,
    const float* __restrict__ c0, __bf16* __restrict__ out,
    float* __restrict__ a_src, float* __restrict__ a_dst)
{
    __shared__ float u2s[8][256];
    __shared__ float c0s[8];
    int tid = threadIdx.x;
    #pragma unroll
    for (int t = 0; t < 8; ++t) u2s[t][tid] = u2[t * 256 + tid];
    if (tid < 8) c0s[tid] = c0[tid];
    __syncthreads();

    int wave = tid >> 6, lane = tid & 63;
    int row = blockIdx.x * 4 + wave;
    float4 v = ((const float4*)(in + (size_t)row * D_MODEL))[lane];
    float s  = v.x + v.y + v.z + v.w;
    float sq = v.x*v.x + v.y*v.y + v.z*v.z + v.w*v.w;
    for (int off = 32; off; off >>= 1) {
        s  += __shfl_xor(s,  off);
        sq += __shfl_xor(sq, off);
    }
    float mean = s * (1.0f / D_MODEL);
    float var  = sq * (1.0f / D_MODEL) - mean * mean;
    float inv  = rsqrtf(var + 1e-6f);
    float4 g = ((const float4*)gamma)[lane];
    float4 b = ((const float4*)beta)[lane];
    float x0 = (v.x - mean) * inv * g.x + b.x;
    float x1 = (v.y - mean) * inv * g.y + b.y;
    float x2 = (v.z - mean) * inv * g.z + b.z;
    float x3 = (v.w - mean) * inv * g.w + b.w;
    bf16x4 o;
    o[0] = f2bf(x0); o[1] = f2bf(x1); o[2] = f2bf(x2); o[3] = f2bf(x3);
    *(bf16x4*)(out + (size_t)row * D_MODEL + lane * 4) = o;

    float p[8];
    #pragma unroll
    for (int k = 0; k < 8; ++k) {
        const float* up = &u2s[k][lane * 4];
        p[k] = x0 * up[0] + x1 * up[1] + x2 * up[2] + x3 * up[3];
    }
    #pragma unroll
    for (int k = 0; k < 8; ++k)
        for (int s2 = 32; s2; s2 >>= 1) p[k] += __shfl_xor(p[k], s2);
    if (lane == 0) {
        f32x4 ps = {p[0] + c0s[0], p[1] + c0s[1], p[2] + c0s[2], p[3] + c0s[3]};
        f32x4 pd = {p[4] + c0s[4], p[5] + c0s[5], p[6] + c0s[6], p[7] + c0s[7]};
        *(f32x4*)(a_src + row * H_HEADS) = ps;
        *(f32x4*)(a_dst + row * H_HEADS) = pd;
    }
}

// -------- bf16 MFMA GEMM: C[M,N] = A[M,K] * B[N,K]^T (+bias)(+resid) --------
#define BM 128
#define BN 128
#define BK 32
#define LDP 40   // LDS row stride (80B): max 2-way bank aliasing (free)

__global__ __launch_bounds__(256) void gemm_bf16_nt(
    const __bf16* __restrict__ A, const __bf16* __restrict__ B,
    int M, int N, int K,
    const float* __restrict__ bias, const float* __restrict__ resid,
    float* __restrict__ outf, __bf16* __restrict__ outb)
{
    __shared__ __bf16 As[BM * LDP];
    __shared__ __bf16 Bs[BN * LDP];
    int tid  = threadIdx.x;
    int lane = tid & 63;
    int w    = tid >> 6;
    int wm   = w >> 1, wn = w & 1;
    int quad = lane >> 4;
    int l16  = lane & 15;
    int m0 = blockIdx.y * BM;
    int n0 = blockIdx.x * BN;

    f32x4 acc[4][4] = {};

    for (int kb = 0; kb < K; kb += BK) {
        bf16x8 areg[2], breg[2];
        #pragma unroll
        for (int t = 0; t < 2; ++t) {
            int c = tid + t * 256;
            int r = c >> 2, p = c & 3;
            areg[t] = *(const bf16x8*)(A + (size_t)(m0 + r) * K + kb + p * 8);
            breg[t] = *(const bf16x8*)(B + (size_t)(n0 + r) * K + kb + p * 8);
        }
        __syncthreads();
        #pragma unroll
        for (int t = 0; t < 2; ++t) {
            int c = tid + t * 256;
            int r = c >> 2, p = c & 3;
            *(bf16x8*)(As + r * LDP + p * 8) = areg[t];
            *(bf16x8*)(Bs + r * LDP + p * 8) = breg[t];
        }
        __syncthreads();
        bf16x8 af[4], bfr[4];
        #pragma unroll
        for (int mt = 0; mt < 4; ++mt)
            af[mt] = *(const bf16x8*)(As + (wm * 64 + mt * 16 + l16) * LDP + quad * 8);
        #pragma unroll
        for (int nt = 0; nt < 4; ++nt)
            bfr[nt] = *(const bf16x8*)(Bs + (wn * 64 + nt * 16 + l16) * LDP + quad * 8);
        #pragma unroll
        for (int mt = 0; mt < 4; ++mt)
            #pragma unroll
            for (int nt = 0; nt < 4; ++nt)
                acc[mt][nt] = __builtin_amdgcn_mfma_f32_16x16x32_bf16(
                    af[mt], bfr[nt], acc[mt][nt], 0, 0, 0);
    }

    int rowb = m0 + wm * 64;
    int colb = n0 + wn * 64;
    #pragma unroll
    for (int nt = 0; nt < 4; ++nt) {
        int col = colb + nt * 16 + l16;
        float bv = bias ? bias[col] : 0.0f;
        #pragma unroll
        for (int mt = 0; mt < 4; ++mt) {
            int row = rowb + mt * 16 + quad * 4;
            #pragma unroll
            for (int r = 0; r < 4; ++r) {
                float v = acc[mt][nt][r] + bv;
                size_t off = (size_t)(row + r) * N + col;
                if (outf) {
                    if (resid) v += resid[off];
                    outf[off] = v;
                } else {
                    outb[off] = f2bf(v);
                }
            }
        }
    }
}

// ---------------- CSR build ----------------
__global__ void hist_kernel(const int* __restrict__ ei, int* __restrict__ deg)
{
    int e = blockIdx.x * blockDim.x + threadIdx.x;
    if (e >= ETOT) return;
    int dst = (e < E_EDGES) ? ei[E_EDGES + e] : (e - E_EDGES);
    atomicAdd(deg + dst, 1);
}

__global__ __launch_bounds__(1024) void scan_kernel(
    const int* __restrict__ deg, int* __restrict__ row_start)
{
    __shared__ int wsum[16];
    int tid = threadIdx.x;
    int lane = tid & 63, wid = tid >> 6;
    int base = tid * 16;
    int local[16];
    int run = 0;
    #pragma unroll
    for (int j = 0; j < 16; ++j) { local[j] = run; run += deg[base + j]; }
    int x = run;
    #pragma unroll
    for (int off = 1; off < 64; off <<= 1) {
        int y = __shfl_up(x, off);
        if (lane >= off) x += y;
    }
    if (lane == 63) wsum[wid] = x;
    __syncthreads();
    if (wid == 0) {
        int wv = (lane < 16) ? wsum[lane] : 0;
        int xx = wv;
        #pragma unroll
        for (int off = 1; off < 16; off <<= 1) {
            int y = __shfl_up(xx, off);
            if (lane >= off) xx += y;
        }
        if (lane < 16) wsum[lane] = xx - wv;
    }
    __syncthreads();
    int excl = wsum[wid] + (x - run);
    #pragma unroll
    for (int j = 0; j < 16; ++j) row_start[base + j] = excl + local[j];
    if (tid == 1023) row_start[N_NODES] = excl + run;
}

__global__ void scatter_kernel(const int* __restrict__ ei,
                               const int* __restrict__ row_start,
                               int* __restrict__ cnt, int* __restrict__ csr_src)
{
    int e = blockIdx.x * blockDim.x + threadIdx.x;
    if (e >= ETOT) return;
    int src, dst;
    if (e < E_EDGES) { src = ei[e]; dst = ei[E_EDGES + e]; }
    else             { src = dst = e - E_EDGES; }
    int pos = atomicAdd(cnt + dst, 1);
    csr_src[row_start[dst] + pos] = src;
}

// ---- fused softmax + aggregation in x_ln domain: one wave per node ----
// agg[i][h*256+d] = (0.25/denom_h) * sum_j exp(l_hj - mx_h) * x_ln[j][d]
__global__ __launch_bounds__(256) void gat_fused(
    const __bf16* __restrict__ x_ln, const float* __restrict__ a_src,
    const float* __restrict__ a_dst, const int* __restrict__ row_start,
    const int* __restrict__ csr_src, __bf16* __restrict__ agg)
{
    int wave = threadIdx.x >> 6, lane = threadIdx.x & 63;
    int i = blockIdx.x * 4 + wave;
    int rs = row_start[i], deg = row_start[i + 1] - rs;
    float4 ad = *(const float4*)(a_dst + i * H_HEADS);

    // pass 1: per-head max (edge-parallel across lanes)
    float mx[4] = {-1e30f, -1e30f, -1e30f, -1e30f};
    for (int e = lane; e < deg; e += 64) {
        int s = csr_src[rs + e];
        float4 as = *(const float4*)(a_src + s * H_HEADS);
        float l0 = as.x + ad.x, l1 = as.y + ad.y, l2 = as.z + ad.z, l3 = as.w + ad.w;
        l0 = (l0 > 0.f) ? l0 : 0.2f * l0;
        l1 = (l1 > 0.f) ? l1 : 0.2f * l1;
        l2 = (l2 > 0.f) ? l2 : 0.2f * l2;
        l3 = (l3 > 0.f) ? l3 : 0.2f * l3;
        mx[0] = fmaxf(mx[0], l0); mx[1] = fmaxf(mx[1], l1);
        mx[2] = fmaxf(mx[2], l2); mx[3] = fmaxf(mx[3], l3);
    }
    #pragma unroll
    for (int h = 0; h < 4; ++h)
        for (int off = 32; off; off >>= 1) mx[h] = fmaxf(mx[h], __shfl_xor(mx[h], off));

    // pass 2: exp + weighted accumulate + denom (uniform edge loop; lane owns 4 ch)
    float acc[4][4] = {};
    float sm0 = 0.f, sm1 = 0.f, sm2 = 0.f, sm3 = 0.f;
    for (int e = 0; e < deg; ++e) {
        int s = csr_src[rs + e];
        float4 as = *(const float4*)(a_src + s * H_HEADS);
        float l0 = as.x + ad.x, l1 = as.y + ad.y, l2 = as.z + ad.z, l3 = as.w + ad.w;
        l0 = (l0 > 0.f) ? l0 : 0.2f * l0;
        l1 = (l1 > 0.f) ? l1 : 0.2f * l1;
        l2 = (l2 > 0.f) ? l2 : 0.2f * l2;
        l3 = (l3 > 0.f) ? l3 : 0.2f * l3;
        float w0 = __expf(l0 - mx[0]), w1 = __expf(l1 - mx[1]);
        float w2 = __expf(l2 - mx[2]), w3 = __expf(l3 - mx[3]);
        sm0 += w0; sm1 += w1; sm2 += w2; sm3 += w3;
        bf16x4 x = *(const bf16x4*)(x_ln + (size_t)s * D_MODEL + lane * 4);
        #pragma unroll
        for (int j = 0; j < 4; ++j) {
            float xv = bf2f(x[j]);
            acc[0][j] = fmaf(w0, xv, acc[0][j]);
            acc[1][j] = fmaf(w1, xv, acc[1][j]);
            acc[2][j] = fmaf(w2, xv, acc[2][j]);
            acc[3][j] = fmaf(w3, xv, acc[3][j]);
        }
    }
    float sc[4] = {0.25f / sm0, 0.25f / sm1, 0.25f / sm2, 0.25f / sm3};
    #pragma unroll
    for (int h = 0; h < 4; ++h) {
        bf16x4 o;
        #pragma unroll
        for (int j = 0; j < 4; ++j) o[j] = f2bf(acc[h][j] * sc[h]);
        *(bf16x4*)(agg + (size_t)i * HC + h * 256 + lane * 4) = o;
    }
}

extern "C" void kernel_launch(void* const* d_in, const int* in_sizes, int n_in,
                              void* d_out, int out_size, void* d_ws, size_t ws_size,
                              hipStream_t stream)
{
    const float* inp      = (const float*)d_in[0];
    const int*   ei       = (const int*)  d_in[1];
    const float* ln_gamma = (const float*)d_in[2];
    const float* ln_beta  = (const float*)d_in[3];
    const float* W1       = (const float*)d_in[4];
    const float* b1       = (const float*)d_in[5];
    const float* W_gat    = (const float*)d_in[6];
    const float* att_src  = (const float*)d_in[7];
    const float* att_dst  = (const float*)d_in[8];
    const float* bias_gat = (const float*)d_in[9];
    const float* W2       = (const float*)d_in[10];
    const float* b2       = (const float*)d_in[11];

    char* ws = (char*)d_ws;
    __bf16* x_ln_bf    = (__bf16*)(ws);                        //  8 MB
    __bf16* agg_bf     = (__bf16*)(ws + (8ull  << 20));        // 32 MB
    __bf16* gnn_out_bf = (__bf16*)(ws + (40ull << 20));        //  8 MB
    __bf16* W2_bf      = (__bf16*)(ws + (48ull << 20));        // 128 KB
    __bf16* Wc2_b      = W2_bf + 65536;                        // 512 KB
    float*  bias_agg   = (float*)(ws + (49ull << 20));         //   1 KB
    float*  t_vec      = bias_agg + 256;                       //   8 KB
    float*  u2         = t_vec + 8 * 256;                      //   8 KB
    float*  c0         = u2 + 8 * 256;                         //  32 B
    float*  a_src_b    = c0 + 8;                               // 256 KB
    float*  a_dst_b    = a_src_b + (size_t)N_NODES * H_HEADS;  // 256 KB
    int*    deg        = (int*)(a_dst_b + (size_t)N_NODES * H_HEADS);
    int*    cnt        = deg + N_NODES;
    int*    row_st     = cnt + N_NODES;
    int*    csr_src    = row_st + N_NODES + 4;

    // zero deg|cnt in one memset
    hipMemsetAsync(deg, 0, 2 * N_NODES * sizeof(int), stream);

    // prep: composite weights + W2 cast; t -> u2/c0; CSR
    prep_w<<<128, 256, 0, stream>>>(W_gat, W1, b1, bias_gat, W2,
                                    Wc2_b, bias_agg, W2_bf);
    make_t<<<8, 256, 0, stream>>>(W_gat, att_src, att_dst, t_vec);
    make_u2<<<8, 256, 0, stream>>>(t_vec, W1, b1, u2, c0);
    hist_kernel<<<(ETOT + 255) / 256, 256, 0, stream>>>(ei, deg);
    scan_kernel<<<1, 1024, 0, stream>>>(deg, row_st);
    scatter_kernel<<<(ETOT + 255) / 256, 256, 0, stream>>>(ei, row_st, cnt, csr_src);

    // dense pipeline
    ln_logits<<<N_NODES / 4, 256, 0, stream>>>(inp, ln_gamma, ln_beta, u2, c0,
                                               x_ln_bf, a_src_b, a_dst_b);
    gat_fused<<<N_NODES / 4, 256, 0, stream>>>(x_ln_bf, a_src_b, a_dst_b,
                                               row_st, csr_src, agg_bf);
    gemm_bf16_nt<<<dim3(C_CH / BN, N_NODES / BM), 256, 0, stream>>>(
        agg_bf, Wc2_b, N_NODES, C_CH, HC, bias_agg, nullptr, nullptr, gnn_out_bf);
    gemm_bf16_nt<<<dim3(D_MODEL / BN, N_NODES / BM), 256, 0, stream>>>(
        gnn_out_bf, W2_bf, N_NODES, D_MODEL, D_MODEL, b2, inp, (float*)d_out, nullptr);
}

// Round 7
// 205.582 us; speedup vs baseline: 1.2780x; 1.2780x over previous
//
#include <hip/hip_runtime.h>
#include <math.h>

#define N_NODES 16384
#define D_MODEL 256
#define H_HEADS 4
#define C_CH 256
#define E_EDGES 65536
#define ETOT (E_EDGES + N_NODES)
#define HC 1024

typedef __bf16 bf16x8 __attribute__((ext_vector_type(8)));
typedef __bf16 bf16x4 __attribute__((ext_vector_type(4)));
typedef float f32x4 __attribute__((ext_vector_type(4)));

__device__ __forceinline__ __bf16 f2bf(float f) { return (__bf16)f; }
__device__ __forceinline__ float bf2f(__bf16 b) { return (float)b; }

// ---- compose: blocks 0..1023 -> one Wc row each; 1024..1087 cast W2 ----
// Wc[o][d] = sum_k Wg[o][k]*W1[k][d];  bias_c[o] = dot(Wg[o,:], b1)
// Wc2_b[c][h*256+d] = bf16(Wc[h*256+c][d])  (layout for post-agg GEMM)
__global__ __launch_bounds__(256) void compose(
    const float* __restrict__ Wg, const float* __restrict__ W1,
    const float* __restrict__ b1, const float* __restrict__ W2,
    float* __restrict__ Wc_f, __bf16* __restrict__ Wc2_b,
    float* __restrict__ bias_c, __bf16* __restrict__ W2_bf)
{
    int b = blockIdx.x;
    int tid = threadIdx.x;
    if (b >= 1024) {   // cast W2: 64 blocks x 1024 elems
        int i = (b - 1024) * 1024 + tid * 4;
        float4 v = *(const float4*)(W2 + i);
        bf16x4 o;
        o[0] = f2bf(v.x); o[1] = f2bf(v.y); o[2] = f2bf(v.z); o[3] = f2bf(v.w);
        *(bf16x4*)(W2_bf + i) = o;
        return;
    }
    int o = b, h = o >> 8, c = o & 255, d = tid;
    const float* wrow = Wg + (size_t)o * 256;   // uniform across lanes -> s_loads
    float acc = 0.f;
    #pragma unroll 8
    for (int k = 0; k < 256; ++k)
        acc = fmaf(wrow[k], W1[(size_t)k * 256 + d], acc);
    Wc_f[(size_t)o * 256 + d] = acc;
    Wc2_b[(size_t)c * 1024 + h * 256 + d] = f2bf(acc);
    // bias_c[o] = dot(wrow, b1)
    float p = wrow[d] * b1[d];
    for (int s = 32; s; s >>= 1) p += __shfl_xor(p, s);
    __shared__ float red[4];
    if ((tid & 63) == 0) red[tid >> 6] = p;
    __syncthreads();
    if (tid == 0) bias_c[o] = red[0] + red[1] + red[2] + red[3];
}

// ---- finish_small: blocks 0..63 u2 partials (atomicAdd, pre-zeroed);
//      block 64: c0[v] + bias_agg[c] ----
__global__ __launch_bounds__(256) void finish_small(
    const float* __restrict__ Wc_f, const float* __restrict__ bias_c,
    const float* __restrict__ att_src, const float* __restrict__ att_dst,
    const float* __restrict__ bg, float* __restrict__ u2,
    float* __restrict__ c0, float* __restrict__ bias_agg)
{
    int b = blockIdx.x;
    int tid = threadIdx.x;
    if (b < 64) {
        int v = b >> 3, sl = b & 7, h = v & 3;
        const float* att = ((v < 4) ? att_src : att_dst) + h * C_CH;
        float acc = 0.f;
        #pragma unroll
        for (int j = 0; j < 32; ++j) {
            int cc = sl * 32 + j;
            acc = fmaf(Wc_f[(size_t)(h * 256 + cc) * 256 + tid], att[cc], acc);
        }
        atomicAdd(&u2[v * 256 + tid], acc);
    } else {
        // c0[v] = dot(bias_c[h*256 .. +256], att[h])
        int v = tid >> 5, l = tid & 31, h = v & 3;
        const float* att = ((v < 4) ? att_src : att_dst) + h * C_CH;
        float t = 0.f;
        #pragma unroll
        for (int j = 0; j < 8; ++j) {
            int cc = l * 8 + j;
            t = fmaf(bias_c[h * 256 + cc], att[cc], t);
        }
        for (int s = 1; s < 32; s <<= 1) t += __shfl_xor(t, s);
        if (l == 0) c0[v] = t;
        // bias_agg[c] = 0.25*sum_h bias_c[h*256+c] + bg[c]
        int cch = tid;
        bias_agg[cch] = 0.25f * (bias_c[cch] + bias_c[256 + cch] +
                                 bias_c[512 + cch] + bias_c[768 + cch]) + bg[cch];
    }
}

// ------- LayerNorm + fused attention logits: one row per wave -------
__global__ __launch_bounds__(256) void ln_logits(
    const float* __restrict__ in, const float* __restrict__ gamma,
    const float* __restrict__ beta, const float* __restrict__ u2,
    const float* __restrict__ c0, __bf16* __restrict__ out,
    float* __restrict__ a_src, float* __restrict__ a_dst)
{
    __shared__ float u2s[8][256];
    __shared__ float c0s[8];
    int tid = threadIdx.x;
    #pragma unroll
    for (int t = 0; t < 8; ++t) u2s[t][tid] = u2[t * 256 + tid];
    if (tid < 8) c0s[tid] = c0[tid];
    __syncthreads();

    int wave = tid >> 6, lane = tid & 63;
    int row = blockIdx.x * 4 + wave;
    float4 v = ((const float4*)(in + (size_t)row * D_MODEL))[lane];
    float s  = v.x + v.y + v.z + v.w;
    float sq = v.x*v.x + v.y*v.y + v.z*v.z + v.w*v.w;
    for (int off = 32; off; off >>= 1) {
        s  += __shfl_xor(s,  off);
        sq += __shfl_xor(sq, off);
    }
    float mean = s * (1.0f / D_MODEL);
    float var  = sq * (1.0f / D_MODEL) - mean * mean;
    float inv  = rsqrtf(var + 1e-6f);
    float4 g = ((const float4*)gamma)[lane];
    float4 b = ((const float4*)beta)[lane];
    float x0 = (v.x - mean) * inv * g.x + b.x;
    float x1 = (v.y - mean) * inv * g.y + b.y;
    float x2 = (v.z - mean) * inv * g.z + b.z;
    float x3 = (v.w - mean) * inv * g.w + b.w;
    bf16x4 o;
    o[0] = f2bf(x0); o[1] = f2bf(x1); o[2] = f2bf(x2); o[3] = f2bf(x3);
    *(bf16x4*)(out + (size_t)row * D_MODEL + lane * 4) = o;

    float p[8];
    #pragma unroll
    for (int k = 0; k < 8; ++k) {
        const float* up = &u2s[k][lane * 4];
        p[k] = x0 * up[0] + x1 * up[1] + x2 * up[2] + x3 * up[3];
    }
    #pragma unroll
    for (int k = 0; k < 8; ++k)
        for (int s2 = 32; s2; s2 >>= 1) p[k] += __shfl_xor(p[k], s2);
    if (lane == 0) {
        f32x4 ps = {p[0] + c0s[0], p[1] + c0s[1], p[2] + c0s[2], p[3] + c0s[3]};
        f32x4 pd = {p[4] + c0s[4], p[5] + c0s[5], p[6] + c0s[6], p[7] + c0s[7]};
        *(f32x4*)(a_src + row * H_HEADS) = ps;
        *(f32x4*)(a_dst + row * H_HEADS) = pd;
    }
}

// -------- bf16 MFMA GEMM: C[M,N] = A[M,K] * B[N,K]^T (+bias)(+resid) --------
#define BM 128
#define BN 128
#define BK 32
#define LDP 40   // LDS row stride (80B): max 2-way bank aliasing (free)

__global__ __launch_bounds__(256) void gemm_bf16_nt(
    const __bf16* __restrict__ A, const __bf16* __restrict__ B,
    int M, int N, int K,
    const float* __restrict__ bias, const float* __restrict__ resid,
    float* __restrict__ outf, __bf16* __restrict__ outb)
{
    __shared__ __bf16 As[BM * LDP];
    __shared__ __bf16 Bs[BN * LDP];
    int tid  = threadIdx.x;
    int lane = tid & 63;
    int w    = tid >> 6;
    int wm   = w >> 1, wn = w & 1;
    int quad = lane >> 4;
    int l16  = lane & 15;
    int m0 = blockIdx.y * BM;
    int n0 = blockIdx.x * BN;

    f32x4 acc[4][4] = {};

    for (int kb = 0; kb < K; kb += BK) {
        bf16x8 areg[2], breg[2];
        #pragma unroll
        for (int t = 0; t < 2; ++t) {
            int c = tid + t * 256;
            int r = c >> 2, p = c & 3;
            areg[t] = *(const bf16x8*)(A + (size_t)(m0 + r) * K + kb + p * 8);
            breg[t] = *(const bf16x8*)(B + (size_t)(n0 + r) * K + kb + p * 8);
        }
        __syncthreads();
        #pragma unroll
        for (int t = 0; t < 2; ++t) {
            int c = tid + t * 256;
            int r = c >> 2, p = c & 3;
            *(bf16x8*)(As + r * LDP + p * 8) = areg[t];
            *(bf16x8*)(Bs + r * LDP + p * 8) = breg[t];
        }
        __syncthreads();
        bf16x8 af[4], bfr[4];
        #pragma unroll
        for (int mt = 0; mt < 4; ++mt)
            af[mt] = *(const bf16x8*)(As + (wm * 64 + mt * 16 + l16) * LDP + quad * 8);
        #pragma unroll
        for (int nt = 0; nt < 4; ++nt)
            bfr[nt] = *(const bf16x8*)(Bs + (wn * 64 + nt * 16 + l16) * LDP + quad * 8);
        #pragma unroll
        for (int mt = 0; mt < 4; ++mt)
            #pragma unroll
            for (int nt = 0; nt < 4; ++nt)
                acc[mt][nt] = __builtin_amdgcn_mfma_f32_16x16x32_bf16(
                    af[mt], bfr[nt], acc[mt][nt], 0, 0, 0);
    }

    int rowb = m0 + wm * 64;
    int colb = n0 + wn * 64;
    #pragma unroll
    for (int nt = 0; nt < 4; ++nt) {
        int col = colb + nt * 16 + l16;
        float bv = bias ? bias[col] : 0.0f;
        #pragma unroll
        for (int mt = 0; mt < 4; ++mt) {
            int row = rowb + mt * 16 + quad * 4;
            #pragma unroll
            for (int r = 0; r < 4; ++r) {
                float v = acc[mt][nt][r] + bv;
                size_t off = (size_t)(row + r) * N + col;
                if (outf) {
                    if (resid) v += resid[off];
                    outf[off] = v;
                } else {
                    outb[off] = f2bf(v);
                }
            }
        }
    }
}

// ---------------- CSR build ----------------
__global__ void hist_kernel(const int* __restrict__ ei, int* __restrict__ deg)
{
    int e = blockIdx.x * blockDim.x + threadIdx.x;
    if (e >= ETOT) return;
    int dst = (e < E_EDGES) ? ei[E_EDGES + e] : (e - E_EDGES);
    atomicAdd(deg + dst, 1);
}

__global__ __launch_bounds__(1024) void scan_kernel(
    const int* __restrict__ deg, int* __restrict__ row_start)
{
    __shared__ int wsum[16];
    int tid = threadIdx.x;
    int lane = tid & 63, wid = tid >> 6;
    int base = tid * 16;
    int local[16];
    int run = 0;
    #pragma unroll
    for (int j = 0; j < 16; ++j) { local[j] = run; run += deg[base + j]; }
    int x = run;
    #pragma unroll
    for (int off = 1; off < 64; off <<= 1) {
        int y = __shfl_up(x, off);
        if (lane >= off) x += y;
    }
    if (lane == 63) wsum[wid] = x;
    __syncthreads();
    if (wid == 0) {
        int wv = (lane < 16) ? wsum[lane] : 0;
        int xx = wv;
        #pragma unroll
        for (int off = 1; off < 16; off <<= 1) {
            int y = __shfl_up(xx, off);
            if (lane >= off) xx += y;
        }
        if (lane < 16) wsum[lane] = xx - wv;
    }
    __syncthreads();
    int excl = wsum[wid] + (x - run);
    #pragma unroll
    for (int j = 0; j < 16; ++j) row_start[base + j] = excl + local[j];
    if (tid == 1023) row_start[N_NODES] = excl + run;
}

__global__ void scatter_kernel(const int* __restrict__ ei,
                               const int* __restrict__ row_start,
                               int* __restrict__ cnt, int* __restrict__ csr_src)
{
    int e = blockIdx.x * blockDim.x + threadIdx.x;
    if (e >= ETOT) return;
    int src, dst;
    if (e < E_EDGES) { src = ei[e]; dst = ei[E_EDGES + e]; }
    else             { src = dst = e - E_EDGES; }
    int pos = atomicAdd(cnt + dst, 1);
    csr_src[row_start[dst] + pos] = src;
}

// ---- fused softmax + aggregation in x_ln domain: one wave per node ----
// agg[i][h*256+d] = (0.25/denom_h) * sum_j exp(l_hj - mx_h) * x_ln[j][d]
__global__ __launch_bounds__(256) void gat_fused(
    const __bf16* __restrict__ x_ln, const float* __restrict__ a_src,
    const float* __restrict__ a_dst, const int* __restrict__ row_start,
    const int* __restrict__ csr_src, __bf16* __restrict__ agg)
{
    int wave = threadIdx.x >> 6, lane = threadIdx.x & 63;
    int i = blockIdx.x * 4 + wave;
    int rs = row_start[i], deg = row_start[i + 1] - rs;
    float4 ad = *(const float4*)(a_dst + i * H_HEADS);

    // pass 1: per-head max (edge-parallel across lanes)
    float mx[4] = {-1e30f, -1e30f, -1e30f, -1e30f};
    for (int e = lane; e < deg; e += 64) {
        int s = csr_src[rs + e];
        float4 as = *(const float4*)(a_src + s * H_HEADS);
        float l0 = as.x + ad.x, l1 = as.y + ad.y, l2 = as.z + ad.z, l3 = as.w + ad.w;
        l0 = (l0 > 0.f) ? l0 : 0.2f * l0;
        l1 = (l1 > 0.f) ? l1 : 0.2f * l1;
        l2 = (l2 > 0.f) ? l2 : 0.2f * l2;
        l3 = (l3 > 0.f) ? l3 : 0.2f * l3;
        mx[0] = fmaxf(mx[0], l0); mx[1] = fmaxf(mx[1], l1);
        mx[2] = fmaxf(mx[2], l2); mx[3] = fmaxf(mx[3], l3);
    }
    #pragma unroll
    for (int h = 0; h < 4; ++h)
        for (int off = 32; off; off >>= 1) mx[h] = fmaxf(mx[h], __shfl_xor(mx[h], off));

    // pass 2: exp + weighted accumulate + denom (uniform edge loop; lane owns 4 ch)
    float acc[4][4] = {};
    float sm0 = 0.f, sm1 = 0.f, sm2 = 0.f, sm3 = 0.f;
    for (int e = 0; e < deg; ++e) {
        int s = csr_src[rs + e];
        float4 as = *(const float4*)(a_src + s * H_HEADS);
        float l0 = as.x + ad.x, l1 = as.y + ad.y, l2 = as.z + ad.z, l3 = as.w + ad.w;
        l0 = (l0 > 0.f) ? l0 : 0.2f * l0;
        l1 = (l1 > 0.f) ? l1 : 0.2f * l1;
        l2 = (l2 > 0.f) ? l2 : 0.2f * l2;
        l3 = (l3 > 0.f) ? l3 : 0.2f * l3;
        float w0 = __expf(l0 - mx[0]), w1 = __expf(l1 - mx[1]);
        float w2 = __expf(l2 - mx[2]), w3 = __expf(l3 - mx[3]);
        sm0 += w0; sm1 += w1; sm2 += w2; sm3 += w3;
        bf16x4 x = *(const bf16x4*)(x_ln + (size_t)s * D_MODEL + lane * 4);
        #pragma unroll
        for (int j = 0; j < 4; ++j) {
            float xv = bf2f(x[j]);
            acc[0][j] = fmaf(w0, xv, acc[0][j]);
            acc[1][j] = fmaf(w1, xv, acc[1][j]);
            acc[2][j] = fmaf(w2, xv, acc[2][j]);
            acc[3][j] = fmaf(w3, xv, acc[3][j]);
        }
    }
    float sc[4] = {0.25f / sm0, 0.25f / sm1, 0.25f / sm2, 0.25f / sm3};
    #pragma unroll
    for (int h = 0; h < 4; ++h) {
        bf16x4 o;
        #pragma unroll
        for (int j = 0; j < 4; ++j) o[j] = f2bf(acc[h][j] * sc[h]);
        *(bf16x4*)(agg + (size_t)i * HC + h * 256 + lane * 4) = o;
    }
}

extern "C" void kernel_launch(void* const* d_in, const int* in_sizes, int n_in,
                              void* d_out, int out_size, void* d_ws, size_t ws_size,
                              hipStream_t stream)
{
    const float* inp      = (const float*)d_in[0];
    const int*   ei       = (const int*)  d_in[1];
    const float* ln_gamma = (const float*)d_in[2];
    const float* ln_beta  = (const float*)d_in[3];
    const float* W1       = (const float*)d_in[4];
    const float* b1       = (const float*)d_in[5];
    const float* W_gat    = (const float*)d_in[6];
    const float* att_src  = (const float*)d_in[7];
    const float* att_dst  = (const float*)d_in[8];
    const float* bias_gat = (const float*)d_in[9];
    const float* W2       = (const float*)d_in[10];
    const float* b2       = (const float*)d_in[11];

    char* ws = (char*)d_ws;
    __bf16* x_ln_bf    = (__bf16*)(ws);                        //  8 MB
    __bf16* agg_bf     = (__bf16*)(ws + (8ull  << 20));        // 32 MB
    __bf16* gnn_out_bf = (__bf16*)(ws + (40ull << 20));        //  8 MB
    __bf16* W2_bf      = (__bf16*)(ws + (48ull << 20));        // 128 KB
    __bf16* Wc2_b      = W2_bf + 65536;                        // 512 KB
    float*  Wc_f       = (float*)(ws + (49ull << 20));         //   1 MB
    float*  bias_c     = (float*)(ws + (50ull << 20));         //   4 KB
    float*  bias_agg   = bias_c + 1024;                        //   1 KB
    float*  a_src_b    = bias_agg + 256;                       // 256 KB
    float*  a_dst_b    = a_src_b + (size_t)N_NODES * H_HEADS;  // 256 KB
    float*  u2         = a_dst_b + (size_t)N_NODES * H_HEADS;  // zero-region start
    float*  c0         = u2 + 8 * 256;
    int*    deg        = (int*)(c0 + 8);
    int*    cnt        = deg + N_NODES;                        // zero-region end
    int*    row_st     = cnt + N_NODES;
    int*    csr_src    = row_st + N_NODES + 4;

    // zero u2|c0|deg|cnt in one memset
    size_t zbytes = (8 * 256 + 8) * sizeof(float) + 2 * N_NODES * sizeof(int);
    hipMemsetAsync(u2, 0, zbytes, stream);

    // prep: composite weights (+W2 cast), small vectors, CSR
    compose<<<1088, 256, 0, stream>>>(W_gat, W1, b1, W2, Wc_f, Wc2_b, bias_c, W2_bf);
    finish_small<<<65, 256, 0, stream>>>(Wc_f, bias_c, att_src, att_dst, bias_gat,
                                         u2, c0, bias_agg);
    hist_kernel<<<(ETOT + 255) / 256, 256, 0, stream>>>(ei, deg);
    scan_kernel<<<1, 1024, 0, stream>>>(deg, row_st);
    scatter_kernel<<<(ETOT + 255) / 256, 256, 0, stream>>>(ei, row_st, cnt, csr_src);

    // dense pipeline
    ln_logits<<<N_NODES / 4, 256, 0, stream>>>(inp, ln_gamma, ln_beta, u2, c0,
                                               x_ln_bf, a_src_b, a_dst_b);
    gat_fused<<<N_NODES / 4, 256, 0, stream>>>(x_ln_bf, a_src_b, a_dst_b,
                                               row_st, csr_src, agg_bf);
    gemm_bf16_nt<<<dim3(C_CH / BN, N_NODES / BM), 256, 0, stream>>>(
        agg_bf, Wc2_b, N_NODES, C_CH, HC, bias_agg, nullptr, nullptr, gnn_out_bf);
    gemm_bf16_nt<<<dim3(D_MODEL / BN, N_NODES / BM), 256, 0, stream>>>(
        gnn_out_bf, W2_bf, N_NODES, D_MODEL, D_MODEL, b2, inp, (float*)d_out, nullptr);
}